// Round 9
// baseline (103.213 us; speedup 1.0000x reference)
//
#include <hip/hip_runtime.h>
#include <math.h>

#define WS 21
#define KWIN 43            // 2*WS+1
#define H 128
#define W 128
#define B 2
#define C 3
#define HW (H * W)
#define CHW (C * H * W)
#define NPIX (B * H * W)   // 32768
#define SIGMA_SPACE (1.0f / 98.0f)
#define NSPLIT 16
#define EXT 170            // W + 2*WS
#define RSTRIDE 171        // padded LDS row stride (uint2 units)
#define SQ_THR_FP16 0.17f  // fp16-screen threshold (validated r7/r8, absmax 0)
#define NEG_SC_LOG2E 72.1347520445f   // 50*log2(e)
#define SG 17.509290f      // sum_{k=-21..21} exp(-k^2/98)

typedef _Float16 h2_t __attribute__((ext_vector_type(2)));

__device__ __forceinline__ int reflect_idx(int t, int n) {
    if (t < 0) t = -t;
    if (t > n - 1) t = 2 * (n - 1) - t;
    return t;
}

// ---------------- K1: H-pass conv (256 thr) + Sobel mask (128 thr) + out zero ----------------
__global__ __launch_bounds__(384)
void prep_kernel(const float* __restrict__ orig,
                 const float* __restrict__ smooth,
                 float* __restrict__ Gh, float* __restrict__ Qh,
                 float* __restrict__ mask, float* __restrict__ out) {
    __shared__ float row[EXT], rsq[EXT], wt[KWIN];
    const int bid = blockIdx.x;      // bc*128 + h ; bc = b*3+c
    const int h   = bid & 127;
    const int bc  = bid >> 7;
    const int t   = threadIdx.x;
    if (bid == 0 && t == 0) out[0] = 0.f;
    if (t < KWIN) { int k = t - WS; wt[t] = __expf(-SIGMA_SPACE * (float)(k * k)); }
    const float* src = smooth + bc * HW + h * W;
    if (t < EXT) {
        float v = src[reflect_idx(t - WS, W)];
        row[t] = v; rsq[t] = v * v;
    }
    __syncthreads();
    if (t < 256) {
        const int w = t & 127;
        const float* buf = (t < 128) ? row : rsq;
        float acc = 0.f;
#pragma unroll
        for (int y = 0; y < KWIN; ++y) acc = fmaf(wt[y], buf[w + y], acc);
        ((t < 128) ? Gh : Qh)[bid * W + w] = acc;
    } else if (bc == 0 || bc == 3) {
        const int b = bc / 3;
        const int w = t - 256;
        const float* ob = orig   + b * CHW;
        const float* sb = smooth + b * CHW;
        int hm = reflect_idx(h - 1, H), hp = reflect_idx(h + 1, H);
        int wm = reflect_idx(w - 1, W), wp = reflect_idx(w + 1, W);
        float eo = 0.f, es = 0.f;
#pragma unroll
        for (int c = 0; c < C; ++c) {
            const float* po = ob + c * HW;
            const float* ps = sb + c * HW;
            {
                float a00 = po[hm * W + wm], a01 = po[hm * W + w], a02 = po[hm * W + wp];
                float a10 = po[h  * W + wm],                        a12 = po[h  * W + wp];
                float a20 = po[hp * W + wm], a21 = po[hp * W + w], a22 = po[hp * W + wp];
                float gx = (a02 - a00) + 2.f * (a12 - a10) + (a22 - a20);
                float gy = (a20 - a00) + 2.f * (a21 - a01) + (a22 - a02);
                eo += sqrtf(gx * gx + gy * gy);
            }
            {
                float a00 = ps[hm * W + wm], a01 = ps[hm * W + w], a02 = ps[hm * W + wp];
                float a10 = ps[h  * W + wm],                        a12 = ps[h  * W + wp];
                float a20 = ps[hp * W + wm], a21 = ps[hp * W + w], a22 = ps[hp * W + wp];
                float gx = (a02 - a00) + 2.f * (a12 - a10) + (a22 - a20);
                float gy = (a20 - a00) + 2.f * (a21 - a01) + (a22 - a02);
                es += sqrtf(gx * gx + gy * gy);
            }
        }
        float m = ((eo < 20.0f) && ((es - eo) > 10.0f)) ? 1.0f : 0.0f;
        mask[(b << 14) + (h << 7) + w] = m;
    }
}

// ---------------- K2: V-pass + large-term (r4-validated), split 4x over x-chunks --------------
__global__ __launch_bounds__(256)
void al_kernel(const float* __restrict__ smooth,
               const float* __restrict__ Gh, const float* __restrict__ Qh,
               const float* __restrict__ mask, float* __restrict__ out) {
    __shared__ float wt[KWIN];
    __shared__ float red[4];
    const int t = threadIdx.x;
    if (t < KWIN) { int k = t - WS; wt[t] = __expf(-SIGMA_SPACE * (float)(k * k)); }
    __syncthreads();

    const int xc  = blockIdx.x & 3;
    const int pb  = blockIdx.x >> 2;
    const int pix = pb * 256 + t;
    const int b = pix >> 14, hw = pix & 16383, h = hw >> 7, w = hw & 127;

    const float* sb  = smooth + b * CHW;
    const float* GhB = Gh + b * 3 * HW;
    const float* QhB = Qh + b * 3 * HW;
    float s0 = sb[hw], s1 = sb[HW + hw], s2 = sb[2 * HW + hw];
    const float n0 = s0 * s0 * SG, n1 = s1 * s1 * SG, n2 = s2 * s2 * SG;
    const float t0 = -2.f * s0, t1 = -2.f * s1, t2 = -2.f * s2;

    float acc = 0.f;
    const int x0 = xc * 11, x1 = (x0 + 11 < KWIN) ? x0 + 11 : KWIN;
    for (int x = x0; x < x1; ++x) {
        int r = reflect_idx(h + x - WS, H);
        int a = r * W + w;
        float g = (n0 + fmaf(t0, GhB[a], QhB[a]))
                + (n1 + fmaf(t1, GhB[HW + a], QhB[HW + a]))
                + (n2 + fmaf(t2, GhB[2 * HW + a], QhB[2 * HW + a]));
        acc = fmaf(wt[x], g, acc);
    }
    float r = mask[pix] * acc;

#pragma unroll
    for (int off = 32; off > 0; off >>= 1) r += __shfl_down(r, off, 64);
    int lane = t & 63, wave = t >> 6;
    if (lane == 0) red[wave] = r;
    __syncthreads();
    if (t == 0) atomicAdd(out, (red[0] + red[1] + red[2] + red[3]) * (1.0f / (float)NPIX));
}

// ---- K3: 4-centers-per-thread sliding fp16 screen; survivors gathered from global ----
#define DECL_CENTER(c) \
    float o0c##c, o1c##c, o2c##c, s0c##c, s1c##c, s2c##c, thr##c; \
    h2_t c01h##c, c2xh##c; \
    { int hw = h * W + (w0 + (c)); \
      o0c##c = ob[hw]; o1c##c = ob[HW + hw]; o2c##c = ob[2 * HW + hw]; \
      s0c##c = sb[hw]; s1c##c = sb[HW + hw]; s2c##c = sb[2 * HW + hw]; \
      c01h##c = (h2_t){ (_Float16)o0c##c, (_Float16)o1c##c }; \
      c2xh##c = (h2_t){ (_Float16)o2c##c, (_Float16)0.f }; \
      thr##c = (mask[(b << 14) + (h << 7) + (w0 + (c))] == 0.0f) ? SQ_THR_FP16 : -1.0f; }

#define SCREEN1(c) \
    if (i >= (c) && i <= 42 + (c)) { \
        const int yi = i - (c); \
        h2_t d01 = c01h##c - a01; \
        h2_t d2x = c2xh##c - a2x; \
        float sq = __builtin_amdgcn_fdot2(d01, d01, \
                    __builtin_amdgcn_fdot2(d2x, d2x, 0.f, false), false); \
        unsigned bit = (sq < thr##c) ? 1u : 0u; \
        if (yi < 21) mA##c |= bit << (20 - yi); \
        else         mB##c |= bit << (42 - yi); \
    }

#define CONSUME(c) \
    { unsigned ma = mA##c, mb = mB##c; \
      while (ma | mb) { \
        int yi; \
        if (ma) { int p = __builtin_ctz(ma); ma &= ma - 1; yi = 20 - p; } \
        else    { int p = __builtin_ctz(mb); mb &= mb - 1; yi = 42 - p; } \
        int ww = reflect_idx(w0 + (c) + yi - WS, W); \
        int a = rr * W + ww; \
        float on0 = ob[a], on1 = ob[HW + a], on2 = ob[2 * HW + a]; \
        float sn0 = sb[a], sn1 = sb[HW + a], sn2 = sb[2 * HW + a]; \
        float g0 = o0c##c - on0, g1 = o1c##c - on1, g2 = o2c##c - on2; \
        float sq = fmaf(g0, g0, fmaf(g1, g1, g2 * g2)); \
        float tt = -NEG_SC_LOG2E * sq; \
        float d0 = fabsf(s0c##c - sn0), d1 = fabsf(s1c##c - sn1), d2 = fabsf(s2c##c - sn2); \
        accS += __builtin_amdgcn_exp2f(fmaf(0.8f, __builtin_amdgcn_logf(d0), tt)) \
              + __builtin_amdgcn_exp2f(fmaf(0.8f, __builtin_amdgcn_logf(d1), tt)) \
              + __builtin_amdgcn_exp2f(fmaf(0.8f, __builtin_amdgcn_logf(d2), tt)); \
      } }

__global__ __launch_bounds__(256, 2)
void screen_kernel(const float* __restrict__ orig,
                   const float* __restrict__ smooth,
                   const float* __restrict__ mask,
                   float* __restrict__ out) {
    __shared__ uint2 oA[8 * RSTRIDE];   // fp16 (o0,o1),(o2,0); 8 rows, reflect pre-applied
    __shared__ float red[4];

    const int t     = threadIdx.x;
    const int split = blockIdx.x & 15;          // xi-slice
    const int rb    = (blockIdx.x >> 4) & 15;   // row block (8 rows)
    const int b     = blockIdx.x >> 8;
    const int h0    = rb * 8;
    const int r     = t & 7;                    // row within block
    const int g     = t >> 3;                   // column group (0..31)
    const int w0    = g * 4;                    // first of 4 centers
    const int h     = h0 + r;
    const int lane  = t & 63;
    const int wave  = t >> 6;

    const float* ob = orig   + b * CHW;
    const float* sb = smooth + b * CHW;

    DECL_CENTER(0) DECL_CENTER(1) DECL_CENTER(2) DECL_CENTER(3)

    // staging descriptors: 1360 uint2 slots (8 rows x 170), 6 per thread
    int rowj[6], scj[6], wsl[6];
#pragma unroll
    for (int j = 0; j < 6; ++j) {
        int idx = t + 256 * j;
        if (idx < 1360) {
            int rw = idx / 170, e = idx - 170 * rw;
            rowj[j] = rw;
            scj[j]  = reflect_idx(e - WS, W);
            wsl[j]  = rw * RSTRIDE + e;
        } else {
            rowj[j] = 0; scj[j] = 0; wsl[j] = -1;
        }
    }

    float accS = 0.f;
    const int base = r * RSTRIDE + w0;

    for (int xi = split; xi < KWIN; xi += NSPLIT) {
        const int x = xi - WS;
        __syncthreads();                        // previous screen done reading LDS
#pragma unroll
        for (int j = 0; j < 6; ++j) {
            if (wsl[j] >= 0) {
                int sr = reflect_idx(h0 + rowj[j] + x, H);
                const float* p = ob + sr * W + scj[j];
                float l0 = p[0], l1 = p[HW], l2 = p[2 * HW];
                h2_t v01 = { (_Float16)l0, (_Float16)l1 };
                h2_t v2x = { (_Float16)l2, (_Float16)0.f };
                oA[wsl[j]] = make_uint2(__builtin_bit_cast(unsigned, v01),
                                        __builtin_bit_cast(unsigned, v2x));
            }
        }
        __syncthreads();                        // staging visible

        const int rr = reflect_idx(h + x, H);   // this thread's source row

        unsigned mA0 = 0u, mB0 = 0u, mA1 = 0u, mB1 = 0u;
        unsigned mA2 = 0u, mB2 = 0u, mA3 = 0u, mB3 = 0u;
#pragma unroll
        for (int i = 0; i < 46; ++i) {          // sliding e-sweep: 46 reads -> 172 screens
            uint2 vv = oA[base + i];
            h2_t a01 = __builtin_bit_cast(h2_t, vv.x);
            h2_t a2x = __builtin_bit_cast(h2_t, vv.y);
            SCREEN1(0) SCREEN1(1) SCREEN1(2) SCREEN1(3)
        }
        if (x == 0) {                           // self-pair term is exactly 0
            mB0 &= ~(1u << 21); mB1 &= ~(1u << 21);
            mB2 &= ~(1u << 21); mB3 &= ~(1u << 21);
        }

        CONSUME(0) CONSUME(1) CONSUME(2) CONSUME(3)
    }

#pragma unroll
    for (int off = 32; off > 0; off >>= 1) accS += __shfl_down(accS, off, 64);
    if (lane == 0) red[wave] = accS;
    __syncthreads();
    if (t == 0) atomicAdd(out, (red[0] + red[1] + red[2] + red[3]) * (1.0f / (float)NPIX));
}

extern "C" void kernel_launch(void* const* d_in, const int* in_sizes, int n_in,
                              void* d_out, int out_size, void* d_ws, size_t ws_size,
                              hipStream_t stream) {
    const float* orig   = (const float*)d_in[0];
    const float* smooth = (const float*)d_in[1];
    float* out = (float*)d_out;

    float* Gh  = (float*)d_ws;                   // 98304 floats
    float* Qh  = Gh + B * C * HW;                // 98304 floats
    float* msk = Qh + B * C * HW;                // 32768 floats

    prep_kernel<<<B * C * H, 384, 0, stream>>>(orig, smooth, Gh, Qh, msk, out);
    al_kernel<<<(NPIX / 256) * 4, 256, 0, stream>>>(smooth, Gh, Qh, msk, out);
    screen_kernel<<<B * (H / 8) * NSPLIT, 256, 0, stream>>>(orig, smooth, msk, out);
}

// Round 10
// 87.644 us; speedup vs baseline: 1.1776x; 1.1776x over previous
//
#include <hip/hip_runtime.h>
#include <math.h>

#define WS 21
#define KWIN 43            // 2*WS+1
#define H 128
#define W 128
#define B 2
#define C 3
#define HW (H * W)
#define CHW (C * H * W)
#define NPIX (B * H * W)   // 32768
#define SIGMA_SPACE (1.0f / 98.0f)
#define NSPLIT 8
#define SQ_THR_FP16 0.17f  // fp16-screen threshold (validated r7-r9, absmax 0)
#define NEG_SC_LOG2E 72.1347520445f   // 50*log2(e)
#define SG 17.509290f      // sum_{k=-21..21} exp(-k^2/98)
#define WSLOTS 108         // wave-private LDS slice (106 used, uint2 units)

typedef _Float16 h2_t __attribute__((ext_vector_type(2)));

__device__ __forceinline__ int reflect_idx(int t, int n) {
    if (t < 0) t = -t;
    if (t > n - 1) t = 2 * (n - 1) - t;
    return t;
}

// ---------------- K1: H-pass conv (256 thr) + Sobel mask (128 thr) + out zero ----------------
__global__ __launch_bounds__(384)
void prep_kernel(const float* __restrict__ orig,
                 const float* __restrict__ smooth,
                 float* __restrict__ Gh, float* __restrict__ Qh,
                 float* __restrict__ mask, float* __restrict__ out) {
    __shared__ float row[170], rsq[170], wt[KWIN];
    const int bid = blockIdx.x;      // bc*128 + h ; bc = b*3+c
    const int h   = bid & 127;
    const int bc  = bid >> 7;
    const int t   = threadIdx.x;
    if (bid == 0 && t == 0) out[0] = 0.f;
    if (t < KWIN) { int k = t - WS; wt[t] = __expf(-SIGMA_SPACE * (float)(k * k)); }
    const float* src = smooth + bc * HW + h * W;
    if (t < 170) {
        float v = src[reflect_idx(t - WS, W)];
        row[t] = v; rsq[t] = v * v;
    }
    __syncthreads();
    if (t < 256) {
        const int w = t & 127;
        const float* buf = (t < 128) ? row : rsq;
        float acc = 0.f;
#pragma unroll
        for (int y = 0; y < KWIN; ++y) acc = fmaf(wt[y], buf[w + y], acc);
        ((t < 128) ? Gh : Qh)[bid * W + w] = acc;
    } else if (bc == 0 || bc == 3) {
        const int b = bc / 3;
        const int w = t - 256;
        const float* ob = orig   + b * CHW;
        const float* sb = smooth + b * CHW;
        int hm = reflect_idx(h - 1, H), hp = reflect_idx(h + 1, H);
        int wm = reflect_idx(w - 1, W), wp = reflect_idx(w + 1, W);
        float eo = 0.f, es = 0.f;
#pragma unroll
        for (int c = 0; c < C; ++c) {
            const float* po = ob + c * HW;
            const float* ps = sb + c * HW;
            {
                float a00 = po[hm * W + wm], a01 = po[hm * W + w], a02 = po[hm * W + wp];
                float a10 = po[h  * W + wm],                        a12 = po[h  * W + wp];
                float a20 = po[hp * W + wm], a21 = po[hp * W + w], a22 = po[hp * W + wp];
                float gx = (a02 - a00) + 2.f * (a12 - a10) + (a22 - a20);
                float gy = (a20 - a00) + 2.f * (a21 - a01) + (a22 - a02);
                eo += sqrtf(gx * gx + gy * gy);
            }
            {
                float a00 = ps[hm * W + wm], a01 = ps[hm * W + w], a02 = ps[hm * W + wp];
                float a10 = ps[h  * W + wm],                        a12 = ps[h  * W + wp];
                float a20 = ps[hp * W + wm], a21 = ps[hp * W + w], a22 = ps[hp * W + wp];
                float gx = (a02 - a00) + 2.f * (a12 - a10) + (a22 - a20);
                float gy = (a20 - a00) + 2.f * (a21 - a01) + (a22 - a02);
                es += sqrtf(gx * gx + gy * gy);
            }
        }
        float m = ((eo < 20.0f) && ((es - eo) > 10.0f)) ? 1.0f : 0.0f;
        mask[(b << 14) + (h << 7) + w] = m;
    }
}

// ---- K2: barrier-free wave-private screen + fused AL + exact survivor recompute ----
// Each wave owns one (row, 64-col half, xi-slice). It stages its own 106-element
// extended row into its own LDS slice; no other wave touches it -> NO __syncthreads
// in the K-loop. Staging for xi+NSPLIT is register-prefetched during the screen.
__global__ __launch_bounds__(256)
void screen_kernel(const float* __restrict__ orig,
                   const float* __restrict__ smooth,
                   const float* __restrict__ Gh, const float* __restrict__ Qh,
                   const float* __restrict__ mask,
                   float* __restrict__ out) {
    __shared__ uint2 oA[4 * WSLOTS];    // 4 wave-private slices
    __shared__ float red[4];

    const int t    = threadIdx.x;
    const int wave = t >> 6;
    const int lane = t & 63;
    const int gw   = blockIdx.x * 4 + wave;   // [0, 4096)
    const int split = gw & 7;                 // xi-slice
    const int half  = (gw >> 3) & 1;
    const int h     = (gw >> 4) & 127;
    const int b     = gw >> 11;
    const int w0    = half * 64;
    const int w     = w0 + lane;
    const int wb    = wave * WSLOTS;

    const float* ob  = orig   + b * CHW;
    const float* sb  = smooth + b * CHW;
    const float* GhB = Gh + b * 3 * HW;
    const float* QhB = Qh + b * 3 * HW;

    const int pix = (b << 14) + (h << 7) + w;
    const float m = mask[pix];
    const float thr_l = (m == 0.0f) ? SQ_THR_FP16 : -1.0f;

    float o0c, o1c, o2c, s0c, s1c, s2c;
    {
        int hw = h * W + w;
        o0c = ob[hw]; o1c = ob[HW + hw]; o2c = ob[2 * HW + hw];
        s0c = sb[hw]; s1c = sb[HW + hw]; s2c = sb[2 * HW + hw];
    }
    const h2_t c01h = { (_Float16)o0c, (_Float16)o1c };
    const h2_t c2xh = { (_Float16)o2c, (_Float16)0.f };

    // AL constants (separable-Gaussian identity)
    const float n0 = s0c * s0c * SG, n1 = s1c * s1c * SG, n2 = s2c * s2c * SG;
    const float tc0 = -2.f * s0c, tc1 = -2.f * s1c, tc2 = -2.f * s2c;

    // wave's extended-row source columns (reflection pre-applied, xi-invariant)
    const int  sc1  = reflect_idx(w0 - WS + lane, W);           // element lane
    const bool has2 = (lane < 42);
    const int  sc2  = reflect_idx(w0 + 43 + lane, W);           // element 64+lane

    float accAL = 0.f, accS = 0.f;

    // ---- prologue: prefetch staging for first xi ----
    float a0, a1, a2, b0 = 0.f, b1 = 0.f, b2 = 0.f;
    {
        const int rr0 = reflect_idx(h + split - WS, H);
        const float* prow = ob + rr0 * W;
        a0 = prow[sc1]; a1 = prow[HW + sc1]; a2 = prow[2 * HW + sc1];
        if (has2) { b0 = prow[sc2]; b1 = prow[HW + sc2]; b2 = prow[2 * HW + sc2]; }
    }

    for (int xi = split; xi < KWIN; xi += NSPLIT) {
        const int x  = xi - WS;
        const int rr = reflect_idx(h + x, H);        // wave-uniform source row

        // write this xi's staged row (regs loaded last iter / prologue)
        {
            h2_t v01 = { (_Float16)a0, (_Float16)a1 };
            h2_t v2x = { (_Float16)a2, (_Float16)0.f };
            oA[wb + lane] = make_uint2(__builtin_bit_cast(unsigned, v01),
                                       __builtin_bit_cast(unsigned, v2x));
            if (has2) {
                h2_t u01 = { (_Float16)b0, (_Float16)b1 };
                h2_t u2x = { (_Float16)b2, (_Float16)0.f };
                oA[wb + 64 + lane] = make_uint2(__builtin_bit_cast(unsigned, u01),
                                                __builtin_bit_cast(unsigned, u2x));
            }
        }

        // prefetch next xi's staged row (overlaps with screen below; no barrier in the way)
        const int xin = xi + NSPLIT;
        if (xin < KWIN) {
            const int rrn = reflect_idx(h + xin - WS, H);
            const float* prow = ob + rrn * W;
            a0 = prow[sc1]; a1 = prow[HW + sc1]; a2 = prow[2 * HW + sc1];
            if (has2) { b0 = prow[sc2]; b1 = prow[HW + sc2]; b2 = prow[2 * HW + sc2]; }
        }

        // fused AL term for this pixel at this xi
        {
            const int ga = rr * W + w;
            float G0 = GhB[ga], G1 = GhB[HW + ga], G2 = GhB[2 * HW + ga];
            float Q0 = QhB[ga], Q1 = QhB[HW + ga], Q2 = QhB[2 * HW + ga];
            float xf = (float)x;
            float wtx = __expf(-SIGMA_SPACE * xf * xf);
            float gsum = (n0 + fmaf(tc0, G0, Q0))
                       + (n1 + fmaf(tc1, G1, Q1))
                       + (n2 + fmaf(tc2, G2, Q2));
            accAL = fmaf(wtx, gsum, accAL);
        }

        // ---- branchless fp16 screen over 43 yi (wave-private LDS, no sync) ----
        unsigned mA = 0u, mB_ = 0u;
#pragma unroll
        for (int yi = 0; yi < KWIN; ++yi) {
            uint2 vv = oA[wb + lane + yi];
            h2_t p01 = __builtin_bit_cast(h2_t, vv.x);
            h2_t p2x = __builtin_bit_cast(h2_t, vv.y);
            h2_t d01 = c01h - p01;
            h2_t d2x = c2xh - p2x;
            float sq = __builtin_amdgcn_fdot2(d01, d01,
                        __builtin_amdgcn_fdot2(d2x, d2x, 0.f, false), false);
            unsigned bit = (sq < thr_l) ? 1u : 0u;
            if (yi < 21) mA  = (mA  << 1) | bit;   // bit (20-yi)
            else         mB_ = (mB_ << 1) | bit;   // bit (42-yi)
        }
        if (xi == WS) mB_ &= ~(1u << 21);          // self-pair term is exactly 0

        // ---- immediate consumption: exact fp32 recompute from global (L2-resident) ----
        while (mA | mB_) {
            int yi;
            if (mA) { int p = __builtin_ctz(mA); mA &= mA - 1; yi = 20 - p; }
            else    { int p = __builtin_ctz(mB_); mB_ &= mB_ - 1; yi = 42 - p; }
            int ww = reflect_idx(w + yi - WS, W);
            int a = rr * W + ww;
            float on0 = ob[a], on1 = ob[HW + a], on2 = ob[2 * HW + a];
            float sn0 = sb[a], sn1 = sb[HW + a], sn2 = sb[2 * HW + a];
            float g0 = o0c - on0, g1 = o1c - on1, g2 = o2c - on2;
            float sq = fmaf(g0, g0, fmaf(g1, g1, g2 * g2));
            float tt = -NEG_SC_LOG2E * sq;
            float d0 = fabsf(s0c - sn0), d1 = fabsf(s1c - sn1), d2 = fabsf(s2c - sn2);
            accS += __builtin_amdgcn_exp2f(fmaf(0.8f, __builtin_amdgcn_logf(d0), tt))
                  + __builtin_amdgcn_exp2f(fmaf(0.8f, __builtin_amdgcn_logf(d1), tt))
                  + __builtin_amdgcn_exp2f(fmaf(0.8f, __builtin_amdgcn_logf(d2), tt));
        }
    }

    float r = m * accAL + accS;
#pragma unroll
    for (int off = 32; off > 0; off >>= 1) r += __shfl_down(r, off, 64);
    if (lane == 0) red[wave] = r;
    __syncthreads();                               // only barrier in the kernel
    if (t == 0) atomicAdd(out, (red[0] + red[1] + red[2] + red[3]) * (1.0f / (float)NPIX));
}

extern "C" void kernel_launch(void* const* d_in, const int* in_sizes, int n_in,
                              void* d_out, int out_size, void* d_ws, size_t ws_size,
                              hipStream_t stream) {
    const float* orig   = (const float*)d_in[0];
    const float* smooth = (const float*)d_in[1];
    float* out = (float*)d_out;

    float* Gh  = (float*)d_ws;                   // 98304 floats
    float* Qh  = Gh + B * C * HW;                // 98304 floats
    float* msk = Qh + B * C * HW;                // 32768 floats

    prep_kernel<<<B * C * H, 384, 0, stream>>>(orig, smooth, Gh, Qh, msk, out);
    // 4096 waves = B * H * 2 halves * NSPLIT ; 4 waves/block
    screen_kernel<<<(B * H * 2 * NSPLIT) / 4, 256, 0, stream>>>(orig, smooth, Gh, Qh, msk, out);
}

// Round 11
// 85.363 us; speedup vs baseline: 1.2091x; 1.0267x over previous
//
#include <hip/hip_runtime.h>
#include <math.h>

#define WS 21
#define KWIN 43            // 2*WS+1
#define H 128
#define W 128
#define B 2
#define C 3
#define HW (H * W)
#define CHW (C * H * W)
#define NPIX (B * H * W)   // 32768
#define SIGMA_SPACE (1.0f / 98.0f)
#define NSPLIT 8
#define SQ_THR_FP16 0.17f  // fp16-screen threshold (validated r7-r9, absmax ~0)
#define NEG_SC_LOG2E 72.1347520445f   // 50*log2(e)
#define SG 17.509290f      // sum_{k=-21..21} exp(-k^2/98)
#define WSLOTS 108         // wave-private LDS slice (106 used, uint2 units)

typedef _Float16 h2_t __attribute__((ext_vector_type(2)));

// Compiler-only memory fence. The wave-private LDS pattern relies on HW per-wave
// DS ordering; this stops the compiler from reordering lane-local LDS ops whose
// cross-lane aliasing it cannot see (r10 root cause: absmax 0 -> 1.0).
#define LDS_COMPILER_FENCE() asm volatile("" ::: "memory")

__device__ __forceinline__ int reflect_idx(int t, int n) {
    if (t < 0) t = -t;
    if (t > n - 1) t = 2 * (n - 1) - t;
    return t;
}

// ---------------- K1: H-pass conv (256 thr) + Sobel mask (128 thr) + out zero ----------------
__global__ __launch_bounds__(384)
void prep_kernel(const float* __restrict__ orig,
                 const float* __restrict__ smooth,
                 float* __restrict__ Gh, float* __restrict__ Qh,
                 float* __restrict__ mask, float* __restrict__ out) {
    __shared__ float row[170], rsq[170], wt[KWIN];
    const int bid = blockIdx.x;      // bc*128 + h ; bc = b*3+c
    const int h   = bid & 127;
    const int bc  = bid >> 7;
    const int t   = threadIdx.x;
    if (bid == 0 && t == 0) out[0] = 0.f;
    if (t < KWIN) { int k = t - WS; wt[t] = __expf(-SIGMA_SPACE * (float)(k * k)); }
    const float* src = smooth + bc * HW + h * W;
    if (t < 170) {
        float v = src[reflect_idx(t - WS, W)];
        row[t] = v; rsq[t] = v * v;
    }
    __syncthreads();
    if (t < 256) {
        const int w = t & 127;
        const float* buf = (t < 128) ? row : rsq;
        float acc = 0.f;
#pragma unroll
        for (int y = 0; y < KWIN; ++y) acc = fmaf(wt[y], buf[w + y], acc);
        ((t < 128) ? Gh : Qh)[bid * W + w] = acc;
    } else if (bc == 0 || bc == 3) {
        const int b = bc / 3;
        const int w = t - 256;
        const float* ob = orig   + b * CHW;
        const float* sb = smooth + b * CHW;
        int hm = reflect_idx(h - 1, H), hp = reflect_idx(h + 1, H);
        int wm = reflect_idx(w - 1, W), wp = reflect_idx(w + 1, W);
        float eo = 0.f, es = 0.f;
#pragma unroll
        for (int c = 0; c < C; ++c) {
            const float* po = ob + c * HW;
            const float* ps = sb + c * HW;
            {
                float a00 = po[hm * W + wm], a01 = po[hm * W + w], a02 = po[hm * W + wp];
                float a10 = po[h  * W + wm],                        a12 = po[h  * W + wp];
                float a20 = po[hp * W + wm], a21 = po[hp * W + w], a22 = po[hp * W + wp];
                float gx = (a02 - a00) + 2.f * (a12 - a10) + (a22 - a20);
                float gy = (a20 - a00) + 2.f * (a21 - a01) + (a22 - a02);
                eo += sqrtf(gx * gx + gy * gy);
            }
            {
                float a00 = ps[hm * W + wm], a01 = ps[hm * W + w], a02 = ps[hm * W + wp];
                float a10 = ps[h  * W + wm],                        a12 = ps[h  * W + wp];
                float a20 = ps[hp * W + wm], a21 = ps[hp * W + w], a22 = ps[hp * W + wp];
                float gx = (a02 - a00) + 2.f * (a12 - a10) + (a22 - a20);
                float gy = (a20 - a00) + 2.f * (a21 - a01) + (a22 - a02);
                es += sqrtf(gx * gx + gy * gy);
            }
        }
        float m = ((eo < 20.0f) && ((es - eo) > 10.0f)) ? 1.0f : 0.0f;
        mask[(b << 14) + (h << 7) + w] = m;
    }
}

// ---- K2: barrier-free wave-private screen + fused AL + exact survivor recompute ----
__global__ __launch_bounds__(256)
void screen_kernel(const float* __restrict__ orig,
                   const float* __restrict__ smooth,
                   const float* __restrict__ Gh, const float* __restrict__ Qh,
                   const float* __restrict__ mask,
                   float* __restrict__ out) {
    __shared__ uint2 oA[4 * WSLOTS];    // 4 wave-private slices
    __shared__ float red[4];

    const int t    = threadIdx.x;
    const int wave = t >> 6;
    const int lane = t & 63;
    const int gw   = blockIdx.x * 4 + wave;   // [0, 4096)
    const int split = gw & 7;                 // xi-slice
    const int half  = (gw >> 3) & 1;
    const int h     = (gw >> 4) & 127;
    const int b     = gw >> 11;
    const int w0    = half * 64;
    const int w     = w0 + lane;
    const int wb    = wave * WSLOTS;

    const float* ob  = orig   + b * CHW;
    const float* sb  = smooth + b * CHW;
    const float* GhB = Gh + b * 3 * HW;
    const float* QhB = Qh + b * 3 * HW;

    const int pix = (b << 14) + (h << 7) + w;
    const float m = mask[pix];
    const float thr_l = (m == 0.0f) ? SQ_THR_FP16 : -1.0f;

    float o0c, o1c, o2c, s0c, s1c, s2c;
    {
        int hw = h * W + w;
        o0c = ob[hw]; o1c = ob[HW + hw]; o2c = ob[2 * HW + hw];
        s0c = sb[hw]; s1c = sb[HW + hw]; s2c = sb[2 * HW + hw];
    }
    const h2_t c01h = { (_Float16)o0c, (_Float16)o1c };
    const h2_t c2xh = { (_Float16)o2c, (_Float16)0.f };

    // AL constants (separable-Gaussian identity)
    const float n0 = s0c * s0c * SG, n1 = s1c * s1c * SG, n2 = s2c * s2c * SG;
    const float tc0 = -2.f * s0c, tc1 = -2.f * s1c, tc2 = -2.f * s2c;

    // wave's extended-row source columns (reflection pre-applied, xi-invariant)
    const int  sc1  = reflect_idx(w0 - WS + lane, W);           // element lane
    const bool has2 = (lane < 42);
    const int  sc2  = reflect_idx(w0 + 43 + lane, W);           // element 64+lane

    float accAL = 0.f, accS = 0.f;

    // ---- prologue: prefetch staging for first xi ----
    float a0, a1, a2, b0 = 0.f, b1 = 0.f, b2 = 0.f;
    {
        const int rr0 = reflect_idx(h + split - WS, H);
        const float* prow = ob + rr0 * W;
        a0 = prow[sc1]; a1 = prow[HW + sc1]; a2 = prow[2 * HW + sc1];
        if (has2) { b0 = prow[sc2]; b1 = prow[HW + sc2]; b2 = prow[2 * HW + sc2]; }
    }

    for (int xi = split; xi < KWIN; xi += NSPLIT) {
        const int x  = xi - WS;
        const int rr = reflect_idx(h + x, H);        // wave-uniform source row

        // (fence) previous iteration's LDS reads must complete (compiler-order) first
        LDS_COMPILER_FENCE();
        // write this xi's staged row (regs loaded last iter / prologue)
        {
            h2_t v01 = { (_Float16)a0, (_Float16)a1 };
            h2_t v2x = { (_Float16)a2, (_Float16)0.f };
            oA[wb + lane] = make_uint2(__builtin_bit_cast(unsigned, v01),
                                       __builtin_bit_cast(unsigned, v2x));
            if (has2) {
                h2_t u01 = { (_Float16)b0, (_Float16)b1 };
                h2_t u2x = { (_Float16)b2, (_Float16)0.f };
                oA[wb + 64 + lane] = make_uint2(__builtin_bit_cast(unsigned, u01),
                                                __builtin_bit_cast(unsigned, u2x));
            }
        }
        // (fence) screen reads below must not hoist above the writes
        LDS_COMPILER_FENCE();

        // prefetch next xi's staged row (overlaps with screen; no barrier in the way)
        const int xin = xi + NSPLIT;
        if (xin < KWIN) {
            const int rrn = reflect_idx(h + xin - WS, H);
            const float* prow = ob + rrn * W;
            a0 = prow[sc1]; a1 = prow[HW + sc1]; a2 = prow[2 * HW + sc1];
            if (has2) { b0 = prow[sc2]; b1 = prow[HW + sc2]; b2 = prow[2 * HW + sc2]; }
        }

        // fused AL term for this pixel at this xi
        {
            const int ga = rr * W + w;
            float G0 = GhB[ga], G1 = GhB[HW + ga], G2 = GhB[2 * HW + ga];
            float Q0 = QhB[ga], Q1 = QhB[HW + ga], Q2 = QhB[2 * HW + ga];
            float xf = (float)x;
            float wtx = __expf(-SIGMA_SPACE * xf * xf);
            float gsum = (n0 + fmaf(tc0, G0, Q0))
                       + (n1 + fmaf(tc1, G1, Q1))
                       + (n2 + fmaf(tc2, G2, Q2));
            accAL = fmaf(wtx, gsum, accAL);
        }

        // ---- branchless fp16 screen over 43 yi (wave-private LDS, no sync) ----
        unsigned mA = 0u, mB_ = 0u;
#pragma unroll
        for (int yi = 0; yi < KWIN; ++yi) {
            uint2 vv = oA[wb + lane + yi];
            h2_t p01 = __builtin_bit_cast(h2_t, vv.x);
            h2_t p2x = __builtin_bit_cast(h2_t, vv.y);
            h2_t d01 = c01h - p01;
            h2_t d2x = c2xh - p2x;
            float sq = __builtin_amdgcn_fdot2(d01, d01,
                        __builtin_amdgcn_fdot2(d2x, d2x, 0.f, false), false);
            unsigned bit = (sq < thr_l) ? 1u : 0u;
            if (yi < 21) mA  = (mA  << 1) | bit;   // bit (20-yi)
            else         mB_ = (mB_ << 1) | bit;   // bit (42-yi)
        }
        if (xi == WS) mB_ &= ~(1u << 21);          // self-pair term is exactly 0

        // ---- immediate consumption: exact fp32 recompute from global (L2-resident) ----
        while (mA | mB_) {
            int yi;
            if (mA) { int p = __builtin_ctz(mA); mA &= mA - 1; yi = 20 - p; }
            else    { int p = __builtin_ctz(mB_); mB_ &= mB_ - 1; yi = 42 - p; }
            int ww = reflect_idx(w + yi - WS, W);
            int a = rr * W + ww;
            float on0 = ob[a], on1 = ob[HW + a], on2 = ob[2 * HW + a];
            float sn0 = sb[a], sn1 = sb[HW + a], sn2 = sb[2 * HW + a];
            float g0 = o0c - on0, g1 = o1c - on1, g2 = o2c - on2;
            float sq = fmaf(g0, g0, fmaf(g1, g1, g2 * g2));
            float tt = -NEG_SC_LOG2E * sq;
            float d0 = fabsf(s0c - sn0), d1 = fabsf(s1c - sn1), d2 = fabsf(s2c - sn2);
            accS += __builtin_amdgcn_exp2f(fmaf(0.8f, __builtin_amdgcn_logf(d0), tt))
                  + __builtin_amdgcn_exp2f(fmaf(0.8f, __builtin_amdgcn_logf(d1), tt))
                  + __builtin_amdgcn_exp2f(fmaf(0.8f, __builtin_amdgcn_logf(d2), tt));
        }
        // (fence) next iteration's LDS writes must not hoist above this screen
        LDS_COMPILER_FENCE();
    }

    float r = m * accAL + accS;
#pragma unroll
    for (int off = 32; off > 0; off >>= 1) r += __shfl_down(r, off, 64);
    if (lane == 0) red[wave] = r;
    __syncthreads();                               // only barrier in the kernel
    if (t == 0) atomicAdd(out, (red[0] + red[1] + red[2] + red[3]) * (1.0f / (float)NPIX));
}

extern "C" void kernel_launch(void* const* d_in, const int* in_sizes, int n_in,
                              void* d_out, int out_size, void* d_ws, size_t ws_size,
                              hipStream_t stream) {
    const float* orig   = (const float*)d_in[0];
    const float* smooth = (const float*)d_in[1];
    float* out = (float*)d_out;

    float* Gh  = (float*)d_ws;                   // 98304 floats
    float* Qh  = Gh + B * C * HW;                // 98304 floats
    float* msk = Qh + B * C * HW;                // 32768 floats

    prep_kernel<<<B * C * H, 384, 0, stream>>>(orig, smooth, Gh, Qh, msk, out);
    // 4096 waves = B * H * 2 halves * NSPLIT ; 4 waves/block
    screen_kernel<<<(B * H * 2 * NSPLIT) / 4, 256, 0, stream>>>(orig, smooth, Gh, Qh, msk, out);
}